// Round 1
// 303.325 us; speedup vs baseline: 1.0749x; 1.0749x over previous
//
#include <hip/hip_runtime.h>
#include <hip/hip_bf16.h>

#define S_LEN  2048
#define DMODEL 2048
#define NH     32
#define NG     8
#define DK     64
#define DV     64

typedef short bf16x8 __attribute__((ext_vector_type(8)));
typedef float f32x4  __attribute__((ext_vector_type(4)));

__device__ __forceinline__ ushort f32_to_bf16(float f) {
    uint u = __float_as_uint(f);
    return (ushort)((u + 0x7fffu + ((u >> 16) & 1u)) >> 16);   // RNE
}
__device__ __forceinline__ float bf16_to_f32(ushort h) {
    return __uint_as_float(((uint)h) << 16);
}
__device__ __forceinline__ uint pack_bf16x2(float a, float b) {
    return (uint)f32_to_bf16(a) | ((uint)f32_to_bf16(b) << 16);
}

// ---------------------------------------------------------------- cast f32->bf16
__global__ void cast_f32_to_bf16(const float* __restrict__ in,
                                 ushort* __restrict__ out, int n8) {
    int i = blockIdx.x * blockDim.x + threadIdx.x;
    const int stride = gridDim.x * blockDim.x;
    for (; i < n8; i += stride) {
        const float4 a = ((const float4*)in)[2 * i];
        const float4 b = ((const float4*)in)[2 * i + 1];
        uint4 o;
        o.x = (uint)f32_to_bf16(a.x) | ((uint)f32_to_bf16(a.y) << 16);
        o.y = (uint)f32_to_bf16(a.z) | ((uint)f32_to_bf16(a.w) << 16);
        o.z = (uint)f32_to_bf16(b.x) | ((uint)f32_to_bf16(b.y) << 16);
        o.w = (uint)f32_to_bf16(b.z) | ((uint)f32_to_bf16(b.w) << 16);
        ((uint4*)out)[i] = o;
    }
}

// ------------------------------------------------- W[K][N] f32 -> Wt[N][K] bf16
__global__ void transpose_cast_bf16(const float* __restrict__ W,
                                    ushort* __restrict__ Wt, int K, int N) {
    __shared__ float t[32][33];
    const int n0 = blockIdx.x * 32, k0 = blockIdx.y * 32;
    const int tx = threadIdx.x, ty = threadIdx.y;   // 32 x 8
#pragma unroll
    for (int i = 0; i < 4; ++i)
        t[ty + 8 * i][tx] = W[(size_t)(k0 + ty + 8 * i) * N + n0 + tx];
    __syncthreads();
#pragma unroll
    for (int i = 0; i < 4; ++i)
        Wt[(size_t)(n0 + ty + 8 * i) * K + k0 + tx] = f32_to_bf16(t[tx][ty + 8 * i]);
}

// --------------------------------------------- bf16 [R][C] -> [C][R] transpose
__global__ void transpose_bf16(const ushort* __restrict__ in,
                               ushort* __restrict__ out, int R, int C) {
    __shared__ ushort t[32][34];
    const int c0 = blockIdx.x * 32, r0 = blockIdx.y * 32;
    const int tx = threadIdx.x, ty = threadIdx.y;   // 32 x 8
#pragma unroll
    for (int i = 0; i < 4; ++i)
        t[ty + 8 * i][tx] = in[(size_t)(r0 + ty + 8 * i) * C + c0 + tx];
    __syncthreads();
#pragma unroll
    for (int i = 0; i < 4; ++i)
        out[(size_t)(c0 + ty + 8 * i) * R + r0 + tx] = t[tx][ty + 8 * i];
}

// ------------------------------------------------------------- bf16 MFMA GEMM
// C[M][N] = (A[M][K] @ Bt[N][K]^T + bias) * scale.  128(M)x64(N) tile, 4 waves
// stacked in M (each: 32 rows x 64 cols = 2x4 frags of mfma_f32_16x16x32_bf16).
// LDS row stride 40 shorts (2-way bank alias only). Register-prefetch
// pipeline: next k-tile's global loads issue before compute.
template <bool OUT_F32>
__device__ __forceinline__ void gemm_body_128x64(
        const ushort* __restrict__ A, const ushort* __restrict__ Bt,
        const float* __restrict__ bias, void* __restrict__ Cv,
        ushort* As, ushort* Bs, int N, int K, float scale) {
    const int tid  = threadIdx.x;
    const int lane = tid & 63, wave = tid >> 6;
    const int l15 = lane & 15, quad = lane >> 4;
    const int row0 = blockIdx.y * 128, col0 = blockIdx.x * 64;

    f32x4 acc[2][4];
#pragma unroll
    for (int i = 0; i < 2; ++i)
#pragma unroll
        for (int j = 0; j < 4; ++j) { f32x4 z = {0.f,0.f,0.f,0.f}; acc[i][j] = z; }

    // staging coords: A 128x32 (2 b128/thread), B 64x32 (1 b128/thread)
    const int ar = tid >> 1, ak = (tid & 1) * 16;
    const int br = tid >> 2, bk = (tid & 3) * 8;
    const ushort* aptr = A  + (size_t)(row0 + ar) * K + ak;
    const ushort* bptr = Bt + (size_t)(col0 + br) * K + bk;

    bf16x8 a0 = *(const bf16x8*)(aptr);
    bf16x8 a1 = *(const bf16x8*)(aptr + 8);
    bf16x8 b0 = *(const bf16x8*)(bptr);

    for (int k0 = 0; k0 < K; k0 += 32) {
        __syncthreads();
        *(bf16x8*)&As[ar * 40 + ak]     = a0;
        *(bf16x8*)&As[ar * 40 + ak + 8] = a1;
        *(bf16x8*)&Bs[br * 40 + bk]     = b0;
        __syncthreads();

        if (k0 + 32 < K) {
            a0 = *(const bf16x8*)(aptr + k0 + 32);
            a1 = *(const bf16x8*)(aptr + k0 + 40);
            b0 = *(const bf16x8*)(bptr + k0 + 32);
        }

        bf16x8 af[2], bf[4];
#pragma unroll
        for (int mi = 0; mi < 2; ++mi)
            af[mi] = *(const bf16x8*)&As[(wave * 32 + mi * 16 + l15) * 40 + quad * 8];
#pragma unroll
        for (int ni = 0; ni < 4; ++ni)
            bf[ni] = *(const bf16x8*)&Bs[(ni * 16 + l15) * 40 + quad * 8];
#pragma unroll
        for (int mi = 0; mi < 2; ++mi)
#pragma unroll
            for (int ni = 0; ni < 4; ++ni)
                acc[mi][ni] = __builtin_amdgcn_mfma_f32_16x16x32_bf16(
                    af[mi], bf[ni], acc[mi][ni], 0, 0, 0);
    }

#pragma unroll
    for (int mi = 0; mi < 2; ++mi)
#pragma unroll
        for (int ni = 0; ni < 4; ++ni) {
            const int col = col0 + ni * 16 + l15;
            const float bv = bias[col];
#pragma unroll
            for (int reg = 0; reg < 4; ++reg) {
                const int row = row0 + wave * 32 + mi * 16 + quad * 4 + reg;
                const float val = (acc[mi][ni][reg] + bv) * scale;
                if (OUT_F32)
                    ((float*)Cv)[(size_t)row * N + col] = val;
                else
                    ((ushort*)Cv)[(size_t)row * N + col] = f32_to_bf16(val);
            }
        }
}

template <bool OUT_F32>
__global__ __launch_bounds__(256) void gemm_bf16_v2(
        const ushort* __restrict__ A, const ushort* __restrict__ Bt,
        const float* __restrict__ bias, void* __restrict__ Cv, int N, int K,
        float scale) {
    __shared__ ushort As[128 * 40];
    __shared__ ushort Bs[64 * 40];
    gemm_body_128x64<OUT_F32>(A, Bt, bias, Cv, As, Bs, N, K, scale);
}

// K and V projections fused via gridDim.z
__global__ __launch_bounds__(256) void gemm_kv(
        const ushort* __restrict__ Xk, const ushort* __restrict__ Xv,
        const ushort* __restrict__ Wkt, const ushort* __restrict__ Wvt,
        const float* __restrict__ bk, const float* __restrict__ bv,
        ushort* __restrict__ Kb, ushort* __restrict__ Vb, int N, int K) {
    __shared__ ushort As[128 * 40];
    __shared__ ushort Bs[64 * 40];
    if (blockIdx.z == 0)
        gemm_body_128x64<false>(Xk, Wkt, bk, Kb, As, Bs, N, K, 1.0f);
    else
        gemm_body_128x64<false>(Xv, Wvt, bv, Vb, As, Bs, N, K, 1.0f);
}

// ------------------------------------------------------ MFMA flash attention
// Grid (16, 32): block handles q-tiles {bx, 31-bx} of one head sequentially —
// exactly 33 j-tiles per block (perfect causal load balance), 512 blocks.
// 4 waves/block; wave owns a 16-row Q stripe.
//
// SWAPPED-OPERAND version: S^T = mfma(K_frag, Q_frag) puts q in the C-layout
// column (l15) — each lane owns ONE q row. Online-softmax state (m, l) is a
// single scalar per lane; row max/sum = 15 in-lane ops + 2 shfl_xor (16, 32)
// instead of 4x4-stage butterflies. P^T packs into per-wave LDS as [q][key]
// (8B vector stores) and reads back contiguously as the PV B-frag.
// PV computes O^T = mfma(V^T_frag, P^T_frag); V^T LDS tile is already in
// A-frag layout. Scale (1/sqrt(dk) * log2e) is pre-folded into Q; exp = exp2.
// Defer-max rescale (T13): skip O/l rescale while tile max stays within
// 8*log2(e) of running max.
__global__ __launch_bounds__(256) void gqa_attn_mfma(
        const ushort* __restrict__ Qb, const ushort* __restrict__ Kb,
        const ushort* __restrict__ Vt, ushort* __restrict__ Ab) {
    __shared__ ushort Ks[64 * 72];       // [key][d]
    __shared__ ushort Vs[64 * 72];       // [d][key]
    __shared__ ushort Ps[4][16 * 72];    // per-wave P^T as [q][key]

    const int h    = blockIdx.y, g = h >> 2;
    const int tid  = threadIdx.x;
    const int lane = tid & 63, wave = tid >> 6;
    const int l15  = lane & 15, quad = lane >> 4;
    const int NT   = S_LEN / 64;         // 32 q-tiles
    const float DEFER_THR = 11.5416f;    // 8 * log2(e)

    // per-thread staging coordinates (fixed across tiles)
    const int srow = tid >> 2, sch = tid & 3;
    const ushort* kbase = Kb + (size_t)srow * (NG * DK) + g * DK + sch * 16;
    const ushort* vbase = Vt + (size_t)(g * 64 + srow) * S_LEN + sch * 16;

    for (int sel = 0; sel < 2; ++sel) {
        const int qt = sel ? (NT - 1 - (int)blockIdx.x) : (int)blockIdx.x;
        const int qr = qt * 64 + wave * 16;      // wave's first q row

        // Q frags (scale pre-folded at projection time), d=0..31 / 32..63
        bf16x8 qa0, qa1;
        {
            const size_t base = (size_t)(qr + l15) * (NH * DK) + (size_t)h * DK + quad * 8;
            qa0 = *(const bf16x8*)&Qb[base];
            qa1 = *(const bf16x8*)&Qb[base + 32];
        }

        f32x4 o[4];                      // O^T: lane = q (l15); rows = d
#pragma unroll
        for (int dt = 0; dt < 4; ++dt) { f32x4 z = {0.f,0.f,0.f,0.f}; o[dt] = z; }
        float m = -1e30f;                // per-lane (per-q) running max, log2 domain
        float l = 0.f;                   // per-lane running sum

        // preload tile 0
        bf16x8 kr0 = *(const bf16x8*)(kbase);
        bf16x8 kr1 = *(const bf16x8*)(kbase + 8);
        bf16x8 vr0 = *(const bf16x8*)(vbase);
        bf16x8 vr1 = *(const bf16x8*)(vbase + 8);

        for (int jt = 0; jt <= qt; ++jt) {
            __syncthreads();             // prior LDS reads complete
            *(bf16x8*)&Ks[srow * 72 + sch * 16]     = kr0;
            *(bf16x8*)&Ks[srow * 72 + sch * 16 + 8] = kr1;
            *(bf16x8*)&Vs[srow * 72 + sch * 16]     = vr0;
            *(bf16x8*)&Vs[srow * 72 + sch * 16 + 8] = vr1;
            __syncthreads();

            // prefetch tile jt+1 (flies during compute below)
            if (jt < qt) {
                const size_t ko = (size_t)(jt + 1) * 64 * (NG * DK);
                const size_t vo = (size_t)(jt + 1) * 64;
                kr0 = *(const bf16x8*)(kbase + ko);
                kr1 = *(const bf16x8*)(kbase + ko + 8);
                vr0 = *(const bf16x8*)(vbase + vo);
                vr1 = *(const bf16x8*)(vbase + vo + 8);
            }

            // S^T = K Q^T : C-layout col = q (l15), row = key (quad*4+r, +16*kt)
            f32x4 s[4];
#pragma unroll
            for (int kt = 0; kt < 4; ++kt) {
                const bf16x8 kb0 = *(const bf16x8*)&Ks[(kt * 16 + l15) * 72 + quad * 8];
                const bf16x8 kb1 = *(const bf16x8*)&Ks[(kt * 16 + l15) * 72 + 32 + quad * 8];
                f32x4 acc = {0.f, 0.f, 0.f, 0.f};
                acc = __builtin_amdgcn_mfma_f32_16x16x32_bf16(kb0, qa0, acc, 0, 0, 0);
                acc = __builtin_amdgcn_mfma_f32_16x16x32_bf16(kb1, qa1, acc, 0, 0, 0);
                s[kt] = acc;
            }

            // causal mask (diagonal tile only; scale already folded into Q)
            if (jt == qt) {
                const int row = wave * 16 + l15;   // q within the 64-row tile
#pragma unroll
                for (int kt = 0; kt < 4; ++kt)
#pragma unroll
                    for (int r = 0; r < 4; ++r) {
                        const int key = kt * 16 + quad * 4 + r;
                        if (key > row) s[kt][r] = -1e30f;
                    }
            }

            // tile max for this q row: 15 in-lane + cross-quad (xor 16, 32)
            float pmax;
            {
                const float t0 = fmaxf(fmaxf(s[0][0], s[0][1]), fmaxf(s[0][2], s[0][3]));
                const float t1 = fmaxf(fmaxf(s[1][0], s[1][1]), fmaxf(s[1][2], s[1][3]));
                const float t2 = fmaxf(fmaxf(s[2][0], s[2][1]), fmaxf(s[2][2], s[2][3]));
                const float t3 = fmaxf(fmaxf(s[3][0], s[3][1]), fmaxf(s[3][2], s[3][3]));
                pmax = fmaxf(fmaxf(t0, t1), fmaxf(t2, t3));
            }
            pmax = fmaxf(pmax, __shfl_xor(pmax, 16, 64));
            pmax = fmaxf(pmax, __shfl_xor(pmax, 32, 64));

            // defer-max: only rescale when the tile max grew past threshold
            if (!__all(pmax - m <= DEFER_THR)) {
                const float mnew  = fmaxf(m, pmax);
                const float alpha = __builtin_amdgcn_exp2f(m - mnew);
                l *= alpha;
#pragma unroll
                for (int dt = 0; dt < 4; ++dt)
#pragma unroll
                    for (int r = 0; r < 4; ++r) o[dt][r] *= alpha;
                m = mnew;
            }

            float p[4][4];
#pragma unroll
            for (int kt = 0; kt < 4; ++kt)
#pragma unroll
                for (int r = 0; r < 4; ++r)
                    p[kt][r] = __builtin_amdgcn_exp2f(s[kt][r] - m);

            float rsum;
            {
                const float u0 = (p[0][0] + p[0][1]) + (p[0][2] + p[0][3]);
                const float u1 = (p[1][0] + p[1][1]) + (p[1][2] + p[1][3]);
                const float u2 = (p[2][0] + p[2][1]) + (p[2][2] + p[2][3]);
                const float u3 = (p[3][0] + p[3][1]) + (p[3][2] + p[3][3]);
                rsum = (u0 + u1) + (u2 + u3);
            }
            rsum += __shfl_xor(rsum, 16, 64);
            rsum += __shfl_xor(rsum, 32, 64);
            l += rsum;

            // P^T -> per-wave LDS [q][key]: 8B vector stores, contiguous keys
            ushort* Pw = &Ps[wave][0];
#pragma unroll
            for (int kt = 0; kt < 4; ++kt) {
                uint2 uu;
                uu.x = pack_bf16x2(p[kt][0], p[kt][1]);
                uu.y = pack_bf16x2(p[kt][2], p[kt][3]);
                *(uint2*)&Pw[l15 * 72 + kt * 16 + quad * 4] = uu;
            }
            const bf16x8 pa0 = *(const bf16x8*)&Pw[l15 * 72 + quad * 8];
            const bf16x8 pa1 = *(const bf16x8*)&Pw[l15 * 72 + 32 + quad * 8];

            // O^T += V^T P^T : A = V^T tile (already [d][key] in LDS), B = P^T
#pragma unroll
            for (int dt = 0; dt < 4; ++dt) {
                const bf16x8 vb0 = *(const bf16x8*)&Vs[(dt * 16 + l15) * 72 + quad * 8];
                const bf16x8 vb1 = *(const bf16x8*)&Vs[(dt * 16 + l15) * 72 + 32 + quad * 8];
                o[dt] = __builtin_amdgcn_mfma_f32_16x16x32_bf16(vb0, pa0, o[dt], 0, 0, 0);
                o[dt] = __builtin_amdgcn_mfma_f32_16x16x32_bf16(vb1, pa1, o[dt], 0, 0, 0);
            }
        }

        // epilogue: lane holds O^T[d = dt*16 + quad*4 + r][q = l15]
        const float invl = 1.0f / l;
#pragma unroll
        for (int dt = 0; dt < 4; ++dt) {
            uint2 uu;
            uu.x = pack_bf16x2(o[dt][0] * invl, o[dt][1] * invl);
            uu.y = pack_bf16x2(o[dt][2] * invl, o[dt][3] * invl);
            *(uint2*)&Ab[(size_t)(qr + l15) * (NH * DV) + (size_t)h * DV + dt * 16 + quad * 4] = uu;
        }
    }
}

// ---------------------------------------------------------------------------
extern "C" void kernel_launch(void* const* d_in, const int* in_sizes, int n_in,
                              void* d_out, int out_size, void* d_ws, size_t ws_size,
                              hipStream_t stream) {
    const float* queries = (const float*)d_in[0];
    const float* keys    = (const float*)d_in[1];
    const float* values  = (const float*)d_in[2];
    const float* Wq      = (const float*)d_in[3];
    const float* bq      = (const float*)d_in[4];
    const float* Wk      = (const float*)d_in[5];
    const float* bk      = (const float*)d_in[6];
    const float* Wv      = (const float*)d_in[7];
    const float* bv      = (const float*)d_in[8];
    const float* Wo      = (const float*)d_in[9];
    const float* bo      = (const float*)d_in[10];
    float* out = (float*)d_out;

    const size_t MB = 1024 * 1024;
    unsigned char* w = (unsigned char*)d_ws;
    ushort* Xq  = (ushort*)(w + 0 * MB);    // [2048][2048] bf16
    ushort* Xk  = (ushort*)(w + 8 * MB);
    ushort* Xv  = (ushort*)(w + 16 * MB);
    ushort* Wqt = (ushort*)(w + 24 * MB);   // [2048][2048]
    ushort* Wkt = (ushort*)(w + 32 * MB);   // [512][2048]
    ushort* Wvt = (ushort*)(w + 34 * MB);
    ushort* Wot = (ushort*)(w + 36 * MB);   // [2048][2048]
    ushort* Qb  = (ushort*)(w + 44 * MB);   // [2048][2048]
    ushort* Kb  = (ushort*)(w + 52 * MB);   // [2048][512]
    ushort* Vb  = (ushort*)(w + 54 * MB);
    ushort* Ab  = (ushort*)(w + 56 * MB);   // [2048][2048]
    // V^T [512][2048] reuses the Xk region (dead after the K projection)
    ushort* Vtp = (ushort*)(w + 8 * MB);

    const int n8 = (S_LEN * DMODEL) / 8;
    cast_f32_to_bf16<<<1024, 256, 0, stream>>>(queries, Xq, n8);
    cast_f32_to_bf16<<<1024, 256, 0, stream>>>(keys,    Xk, n8);
    cast_f32_to_bf16<<<1024, 256, 0, stream>>>(values,  Xv, n8);

    dim3 tb(32, 8);
    transpose_cast_bf16<<<dim3(2048 / 32, 2048 / 32), tb, 0, stream>>>(Wq, Wqt, DMODEL, 2048);
    transpose_cast_bf16<<<dim3(512 / 32,  2048 / 32), tb, 0, stream>>>(Wk, Wkt, DMODEL, 512);
    transpose_cast_bf16<<<dim3(512 / 32,  2048 / 32), tb, 0, stream>>>(Wv, Wvt, DMODEL, 512);
    transpose_cast_bf16<<<dim3(2048 / 32, 2048 / 32), tb, 0, stream>>>(Wo, Wot, DMODEL, 2048);

    // Q projection: [2048,2048] @ [2048,2048]; fold softmax scale * log2(e)
    const float QSCALE = 0.125f * 1.44269504f;
    gemm_bf16_v2<false><<<dim3(2048 / 64, 2048 / 128), 256, 0, stream>>>(
        Xq, Wqt, bq, Qb, 2048, DMODEL, QSCALE);
    // K and V projections fused (z=0: K, z=1: V)
    gemm_kv<<<dim3(512 / 64, 2048 / 128, 2), 256, 0, stream>>>(
        Xk, Xv, Wkt, Wvt, bk, bv, Kb, Vb, 512, DMODEL);

    // V [2048][512] -> V^T [512][2048]
    transpose_bf16<<<dim3(512 / 32, 2048 / 32), tb, 0, stream>>>(Vb, Vtp, S_LEN, 512);

    // attention: paired q-tiles for perfect causal balance
    gqa_attn_mfma<<<dim3(16, 32), 256, 0, stream>>>(Qb, Kb, Vtp, Ab);

    // O projection: [2048,2048] @ [2048,2048] -> f32 out
    gemm_bf16_v2<true><<<dim3(2048 / 64, 2048 / 128), 256, 0, stream>>>(
        Ab, Wot, bo, out, 2048, DMODEL, 1.0f);
}